// Round 11
// baseline (85.885 us; speedup 1.0000x reference)
//
#include <hip/hip_runtime.h>
#include <hip/hip_bf16.h>

#define B_ 8
#define S_ 2048
#define F_ 1024
#define DK_ 128
#define M_ (B_*S_)          // 16384

typedef unsigned short u16;
typedef short short8 __attribute__((ext_vector_type(8)));
typedef float f32x4 __attribute__((ext_vector_type(4)));
typedef float f32x16 __attribute__((ext_vector_type(16)));

__device__ __forceinline__ u16 f2bf(float f) {
    unsigned int u = __float_as_uint(f);
    u += 0x7FFFu + ((u >> 16) & 1u);    // round-to-nearest-even
    return (u16)(u >> 16);
}
__device__ __forceinline__ unsigned int pack2(float a, float b) {
    return (unsigned int)f2bf(a) | ((unsigned int)f2bf(b) << 16);
}
__device__ __forceinline__ float fexp2(float x) {
#if __has_builtin(__builtin_amdgcn_exp2f)
    return __builtin_amdgcn_exp2f(x);   // raw v_exp_f32 (2^x)
#else
    return exp2f(x);
#endif
}
__device__ __forceinline__ unsigned int cvt_pk_bf16(float lo, float hi) {
    unsigned int r;
    asm volatile("v_cvt_pk_bf16_f32 %0, %1, %2" : "=v"(r) : "v"(lo), "v"(hi));
    return r;
}
// v_permlane32_swap_b32 a, b:  a_hi <-> b_lo.  After: a = {a_lo, b_lo},
// b = {a_hi, b_hi}  (lanes<32 of result a hold a's lows; lanes>=32 hold b's lows).
__device__ __forceinline__ void pl32_swap(unsigned int& a, unsigned int& b) {
    asm volatile("v_permlane32_swap_b32 %0, %1" : "+v"(a), "+v"(b));
}

// ---------------------------------------------------------------------------
// Kernel 1: W [1024][128] fp32 -> WT [3][128][1024] bf16 (transposed).
// w_q gets (1/sqrt(128)) * log2(e) folded in, so softmax uses raw exp2.
// ---------------------------------------------------------------------------
__global__ __launch_bounds__(256) void prep_wt(const float* __restrict__ wq,
                                               const float* __restrict__ wk,
                                               const float* __restrict__ wv,
                                               u16* __restrict__ WT) {
    int id = blockIdx.x * 256 + threadIdx.x;
    if (id >= 3 * DK_ * F_) return;
    int m   = id / (DK_ * F_);
    int rem = id - m * (DK_ * F_);
    int c   = rem / F_;
    int k   = rem - c * F_;
    const float* w = (m == 0) ? wq : (m == 1) ? wk : wv;
    float v = w[k * DK_ + c];
    if (m == 0) v *= 0.12751741951f;   // (1/sqrt(128)) * log2(e)
    WT[id] = f2bf(v);
}

// ---------------------------------------------------------------------------
// Kernel 2: projection GEMM (proven R2-R6 version, unchanged).
// mode 0: qp [16384][128], mode 1: kp [16384][128], mode 2: vpT [128][16384]
// ---------------------------------------------------------------------------
__global__ __launch_bounds__(256, 3) void proj(const float* __restrict__ xq,
                                               const float* __restrict__ xk,
                                               const float* __restrict__ xv,
                                               const u16* __restrict__ WT,
                                               u16* __restrict__ qp,
                                               u16* __restrict__ kp,
                                               u16* __restrict__ vpT) {
    const int mode = blockIdx.y;
    const float* X = (mode == 0) ? xq : (mode == 1) ? xk : xv;
    const u16*   W = WT + mode * (DK_ * F_);

    __shared__ u16 a_lds[64][40];
    __shared__ u16 w_lds[128][40];

    const int t    = threadIdx.x;
    const int lane = t & 63;
    const int wv_  = t >> 6;
    const int l15  = lane & 15, l4 = lane >> 4;
    const int row0 = blockIdx.x * 64;

    f32x4 acc[8];
#pragma unroll
    for (int j = 0; j < 8; ++j) acc[j] = f32x4{0.f, 0.f, 0.f, 0.f};

    for (int k0 = 0; k0 < F_; k0 += 32) {
        {
            int r = t >> 2, kk = (t & 3) * 8;
            const float4* src = (const float4*)(X + (size_t)(row0 + r) * F_ + k0 + kk);
            float4 f0 = src[0], f1 = src[1];
            int4 o0;
            o0.x = pack2(f0.x, f0.y); o0.y = pack2(f0.z, f0.w);
            o0.z = pack2(f1.x, f1.y); o0.w = pack2(f1.z, f1.w);
            *(int4*)&a_lds[r][kk] = o0;
        }
        {
            int c = t >> 1, kk = (t & 1) * 16;
            const int4* src = (const int4*)(W + (size_t)c * F_ + k0 + kk);
            *(int4*)&w_lds[c][kk]     = src[0];
            *(int4*)&w_lds[c][kk + 8] = src[1];
        }
        __syncthreads();

        short8 af = *(const short8*)&a_lds[wv_ * 16 + l15][l4 * 8];
        short8 bf[8];
#pragma unroll
        for (int ct = 0; ct < 8; ++ct)
            bf[ct] = *(const short8*)&w_lds[ct * 16 + l15][l4 * 8];

        if (mode < 2) {
#pragma unroll
            for (int ct = 0; ct < 8; ++ct)
                acc[ct] = __builtin_amdgcn_mfma_f32_16x16x32_bf16(af, bf[ct], acc[ct], 0, 0, 0);
        } else {
#pragma unroll
            for (int ct = 0; ct < 8; ++ct)
                acc[ct] = __builtin_amdgcn_mfma_f32_16x16x32_bf16(bf[ct], af, acc[ct], 0, 0, 0);
        }
        __syncthreads();
    }

    if (mode < 2) {
        u16* OUT = (mode == 0) ? qp : kp;
#pragma unroll
        for (int ct = 0; ct < 8; ++ct)
#pragma unroll
            for (int r = 0; r < 4; ++r) {
                int row = row0 + wv_ * 16 + l4 * 4 + r;
                int col = ct * 16 + l15;
                OUT[(size_t)row * DK_ + col] = f2bf(acc[ct][r]);
            }
    } else {
#pragma unroll
        for (int ct = 0; ct < 8; ++ct)
#pragma unroll
            for (int r = 0; r < 4; ++r) {
                int n = ct * 16 + l4 * 4 + r;
                int m = row0 + wv_ * 16 + l15;
                vpT[(size_t)n * M_ + m] = f2bf(acc[ct][r]);
            }
    }
}

// ---------------------------------------------------------------------------
// Kernel 3: flash attention v4.
// R10's residual ~60us: all 8 waves of the single resident block are
// phase-locked duplicates (same barrier, same stalls) -> zero mutual latency
// hiding. v4: 4-wave blocks (kv_sub x d_half), 32 q rows, grid 512 ->
// TWO independent blocks/CU overlap asynchronously. Loop serial path cut:
// no shfl in softmax (cross-half max only inside rare defer branch; lrun
// kept per-half, combined in epilogue), P repack via v_permlane32_swap
// (VALU) instead of 8 ds_bpermute, QK chain split 4+4.
// ---------------------------------------------------------------------------
union attn_lds_t {
    struct {
        __align__(16) unsigned char kbuf[2][16384];  // [64 kv][256B], swz: col16 ^= row&15
        __align__(16) unsigned char vbuf[2][16384];  // [128 d][128B], swz: chunk ^= row&7
    } s;
    struct { float ob[32][132]; } e;                 // epilogue combine (16.9 KB)
};

__global__ __launch_bounds__(256, 2) void attn(const u16* __restrict__ qp,
                                               const u16* __restrict__ kp,
                                               const u16* __restrict__ vpT,
                                               float* __restrict__ out) {
    __shared__ attn_lds_t u;
    __shared__ float m_lds[2][32], l_lds[2][2][32], gm_lds[32], gl_lds[32];

    const int t      = threadIdx.x;
    const int lane   = t & 63;
    const int wv_    = t >> 6;              // 0..3
    const int kv_sub = wv_ & 1;
    const int d_half = wv_ >> 1;
    const int r31    = lane & 31;
    const int hi     = lane >> 5;

    const int b  = blockIdx.x & 7;
    const int qi = blockIdx.x >> 3;          // 0..63
    const int qrow0 = b * S_ + qi * 32;
    const int kvb0  = b * S_;

    // Q as persistent B-fragments: qf[c] = Q[q=r31][d = c*16 + hi*8 + 0..7]
    short8 qf[8];
#pragma unroll
    for (int c = 0; c < 8; ++c)
        qf[c] = *(const short8*)(qp + (size_t)(qrow0 + r31) * DK_ + c * 16 + hi * 8);

    f32x16 o4[2];
#pragma unroll
    for (int ct = 0; ct < 2; ++ct)
#pragma unroll
        for (int i = 0; i < 16; ++i) o4[ct][i] = 0.f;
    float mrun = -1.0e30f, lrun = 0.f;      // lrun is PER-HALF row sum

    // staging: 256 thr x 4 chunks cover K (1024 int4) and V (1024 int4)
    int4 gk[4], gv[4];
    int kr[4], kc[4], vr[4], vc[4];
#pragma unroll
    for (int j = 0; j < 4; ++j) {
        int f = t + 256 * j;
        kr[j] = f >> 4; kc[j] = f & 15;
        vr[j] = f >> 3; vc[j] = f & 7;
    }

#define LOADT(kvb)                                                                \
    {                                                                             \
        _Pragma("unroll")                                                         \
        for (int j = 0; j < 4; ++j) {                                             \
            gk[j] = *(const int4*)(kp + (size_t)((kvb) + kr[j]) * DK_ + kc[j] * 8);\
            gv[j] = *(const int4*)(vpT + (size_t)vr[j] * M_ + (kvb) + vc[j] * 8); \
        }                                                                         \
    }
#define WRITET(nb)                                                                \
    {                                                                             \
        _Pragma("unroll")                                                         \
        for (int j = 0; j < 4; ++j) {                                             \
            *(int4*)(u.s.kbuf[nb] + kr[j] * 256 + ((kc[j] ^ (kr[j] & 15)) << 4)) = gk[j]; \
            *(int4*)(u.s.vbuf[nb] + vr[j] * 128 + ((vc[j] ^ (vr[j] & 7)) << 4)) = gv[j];  \
        }                                                                         \
    }

    LOADT(kvb0);
    WRITET(0);
    int cur = 0;

    for (int kt = 0; kt < 32; ++kt) {
        __syncthreads();                     // buf[cur] visible; vmcnt already 0

        if (kt < 31) LOADT(kvb0 + (kt + 1) * 64);   // prefetch after barrier

        const unsigned char* kb = u.s.kbuf[cur];
        const unsigned char* vb = u.s.vbuf[cur];

        // ---- K fragments from LDS (swizzled)
        const int krow  = kv_sub * 32 + r31;
        const int kbase = krow * 256;
        const int ksw   = krow & 15;
        short8 kf[8];
#pragma unroll
        for (int c = 0; c < 8; ++c)
            kf[c] = *(const short8*)(kb + kbase + (((c * 2 + hi) ^ ksw) << 4));

        // ---- QK^T, two independent 4-chains then add
        f32x16 sa, sb;
#pragma unroll
        for (int i = 0; i < 16; ++i) { sa[i] = 0.f; sb[i] = 0.f; }
#pragma unroll
        for (int c = 0; c < 4; ++c) {
            sa = __builtin_amdgcn_mfma_f32_32x32x16_bf16(kf[c],     qf[c],     sa, 0, 0, 0);
            sb = __builtin_amdgcn_mfma_f32_32x32x16_bf16(kf[c + 4], qf[c + 4], sb, 0, 0, 0);
        }
        f32x16 st;
#pragma unroll
        for (int i = 0; i < 16; ++i) st[i] = sa[i] + sb[i];

        // ---- per-lane softmax, no cross-lane ops on the common path
        float tm = st[0];
#pragma unroll
        for (int i = 1; i < 16; ++i) tm = fmaxf(tm, st[i]);
        if (__any(tm > mrun + 8.0f)) {       // defer-max: rare
            tm = fmaxf(tm, __shfl_xor(tm, 32, 64));   // cross-half max (rare path)
            float mn = fmaxf(mrun, tm);
            float fs = fexp2(mrun - mn);
            mrun = mn;
            lrun *= fs;
#pragma unroll
            for (int ct = 0; ct < 2; ++ct)
#pragma unroll
                for (int i = 0; i < 16; ++i) o4[ct][i] *= fs;
        }
        float s0 = 0.f, s1 = 0.f;
#pragma unroll
        for (int i = 0; i < 16; i += 2) {
            st[i]     = fexp2(st[i] - mrun);
            st[i + 1] = fexp2(st[i + 1] - mrun);
            s0 += st[i]; s1 += st[i + 1];
        }
        lrun += s0 + s1;                     // per-half sum only

        // ---- P -> bf16 B-fragments via permlane32_swap (no LDS, no selects)
        short8 bp[2];
#pragma unroll
        for (int ch = 0; ch < 2; ++ch) {
            unsigned int A1 = cvt_pk_bf16(st[ch * 8 + 0], st[ch * 8 + 1]);
            unsigned int A2 = cvt_pk_bf16(st[ch * 8 + 2], st[ch * 8 + 3]);
            unsigned int A3 = cvt_pk_bf16(st[ch * 8 + 4], st[ch * 8 + 5]);
            unsigned int A4 = cvt_pk_bf16(st[ch * 8 + 6], st[ch * 8 + 7]);
            pl32_swap(A1, A3);   // A1 = {lo halves} = word0, A3 = {hi halves} = word2
            pl32_swap(A2, A4);   // A2 = word1, A4 = word3
            int4 w;
            w.x = (int)A1; w.y = (int)A2; w.z = (int)A3; w.w = (int)A4;
            bp[ch] = *(short8*)&w;
        }

        // ---- stage write for tile kt+1 (loads landed under QK+softmax)
        if (kt < 31) WRITET(cur ^ 1);

        // ---- PV from LDS V^T (this wave's d_half, kv_sub)
#pragma unroll
        for (int ct = 0; ct < 2; ++ct) {
            const int vrow  = d_half * 64 + ct * 32 + r31;
            const int vbase = vrow * 128;
            const int vsw   = vrow & 7;
#pragma unroll
            for (int ch = 0; ch < 2; ++ch) {
                short8 vf = *(const short8*)(vb + vbase
                                             + (((kv_sub * 4 + ch * 2 + hi) ^ vsw) << 4));
                o4[ct] = __builtin_amdgcn_mfma_f32_32x32x16_bf16(vf, bp[ch], o4[ct], 0, 0, 0);
            }
        }

        cur ^= 1;
    }
#undef LOADT
#undef WRITET

    // ---- epilogue: combine kv_sub partials and half-sums ----
    __syncthreads();                          // done with stage bufs (union reuse)
    if (d_half == 0) {
        l_lds[kv_sub][hi][r31] = lrun;        // per-half sums
        if (lane < 32) m_lds[kv_sub][r31] = mrun;   // cross-half uniform
    }
    __syncthreads();
    if (t < 32) {
        float m0 = m_lds[0][t], m1 = m_lds[1][t];
        float gm = fmaxf(m0, m1);
        float gl = (l_lds[0][0][t] + l_lds[0][1][t]) * fexp2(m0 - gm)
                 + (l_lds[1][0][t] + l_lds[1][1][t]) * fexp2(m1 - gm);
        gm_lds[t] = gm;
        gl_lds[t] = gl;
    }
    __syncthreads();

    const float sc = fexp2(mrun - gm_lds[r31]);
    if (kv_sub == 0) {
#pragma unroll
        for (int ct = 0; ct < 2; ++ct)
#pragma unroll
            for (int i = 0; i < 16; ++i) {
                int d = d_half * 64 + ct * 32 + (i & 3) + 8 * (i >> 2) + 4 * hi;
                u.e.ob[r31][d] = o4[ct][i] * sc;
            }
    }
    __syncthreads();
    if (kv_sub == 1) {
#pragma unroll
        for (int ct = 0; ct < 2; ++ct)
#pragma unroll
            for (int i = 0; i < 16; ++i) {
                int d = d_half * 64 + ct * 32 + (i & 3) + 8 * (i >> 2) + 4 * hi;
                u.e.ob[r31][d] += o4[ct][i] * sc;
            }
    }
    __syncthreads();

    // ---- final store: thread t -> row t>>3 (0..31), cols (t&7)*16..+16
    {
        int row = t >> 3, d0 = (t & 7) * 16;
        float inv = 1.0f / gl_lds[row];
        float* dst = out + (size_t)(qrow0 + row) * DK_ + d0;
#pragma unroll
        for (int j = 0; j < 16; j += 4) {
            float4 v;
            v.x = u.e.ob[row][d0 + j]     * inv;
            v.y = u.e.ob[row][d0 + j + 1] * inv;
            v.z = u.e.ob[row][d0 + j + 2] * inv;
            v.w = u.e.ob[row][d0 + j + 3] * inv;
            *(float4*)(dst + j) = v;
        }
    }
}

// ---------------------------------------------------------------------------
extern "C" void kernel_launch(void* const* d_in, const int* in_sizes, int n_in,
                              void* d_out, int out_size, void* d_ws, size_t ws_size,
                              hipStream_t stream) {
    const float* q  = (const float*)d_in[0];
    const float* k  = (const float*)d_in[1];
    const float* v  = (const float*)d_in[2];
    const float* wq = (const float*)d_in[3];
    const float* wk = (const float*)d_in[4];
    const float* wv = (const float*)d_in[5];
    float* out = (float*)d_out;

    char* ws = (char*)d_ws;
    u16* WT  = (u16*)ws;                                   // 786432 B
    u16* qp  = (u16*)(ws + 786432);                        // 4 MB
    u16* kp  = (u16*)(ws + 786432 + 4194304);              // 4 MB
    u16* vpT = (u16*)(ws + 786432 + 2 * 4194304);          // 4 MB

    prep_wt<<<dim3(1536), dim3(256), 0, stream>>>(wq, wk, wv, WT);
    proj<<<dim3(256, 3), dim3(256), 0, stream>>>(q, k, v, WT, qp, kp, vpT);
    attn<<<dim3(512), dim3(256), 0, stream>>>(qp, kp, vpT, out);
}

// Round 12
// 76.405 us; speedup vs baseline: 1.1241x; 1.1241x over previous
//
#include <hip/hip_runtime.h>
#include <hip/hip_bf16.h>

#define B_ 8
#define S_ 2048
#define F_ 1024
#define DK_ 128
#define M_ (B_*S_)          // 16384

typedef unsigned short u16;
typedef short short8 __attribute__((ext_vector_type(8)));
typedef float f32x4 __attribute__((ext_vector_type(4)));
typedef float f32x16 __attribute__((ext_vector_type(16)));

__device__ __forceinline__ u16 f2bf(float f) {
    unsigned int u = __float_as_uint(f);
    u += 0x7FFFu + ((u >> 16) & 1u);    // round-to-nearest-even
    return (u16)(u >> 16);
}
__device__ __forceinline__ unsigned int pack2(float a, float b) {
    return (unsigned int)f2bf(a) | ((unsigned int)f2bf(b) << 16);
}
__device__ __forceinline__ float fexp2(float x) {
#if __has_builtin(__builtin_amdgcn_exp2f)
    return __builtin_amdgcn_exp2f(x);   // raw v_exp_f32 (2^x)
#else
    return exp2f(x);
#endif
}
__device__ __forceinline__ unsigned int cvt_pk_bf16(float lo, float hi) {
    unsigned int r;
    asm("v_cvt_pk_bf16_f32 %0, %1, %2" : "=v"(r) : "v"(lo), "v"(hi));
    return r;
}
// v_permlane32_swap_b32 a, b:  a_hi <-> b_lo.
__device__ __forceinline__ void pl32_swap(unsigned int& a, unsigned int& b) {
    asm("v_permlane32_swap_b32 %0, %1" : "+v"(a), "+v"(b));
}

// ---------------------------------------------------------------------------
// Kernel 1: W [1024][128] fp32 -> WT [3][128][1024] bf16 (transposed).
// w_q gets (1/sqrt(128)) * log2(e) folded in, so softmax uses raw exp2.
// ---------------------------------------------------------------------------
__global__ __launch_bounds__(256) void prep_wt(const float* __restrict__ wq,
                                               const float* __restrict__ wk,
                                               const float* __restrict__ wv,
                                               u16* __restrict__ WT) {
    int id = blockIdx.x * 256 + threadIdx.x;
    if (id >= 3 * DK_ * F_) return;
    int m   = id / (DK_ * F_);
    int rem = id - m * (DK_ * F_);
    int c   = rem / F_;
    int k   = rem - c * F_;
    const float* w = (m == 0) ? wq : (m == 1) ? wk : wv;
    float v = w[k * DK_ + c];
    if (m == 0) v *= 0.12751741951f;   // (1/sqrt(128)) * log2(e)
    WT[id] = f2bf(v);
}

// ---------------------------------------------------------------------------
// Kernel 2: projection GEMM (proven R2-R6 version, unchanged).
// mode 0: qp [16384][128], mode 1: kp [16384][128], mode 2: vpT [128][16384]
// ---------------------------------------------------------------------------
__global__ __launch_bounds__(256, 3) void proj(const float* __restrict__ xq,
                                               const float* __restrict__ xk,
                                               const float* __restrict__ xv,
                                               const u16* __restrict__ WT,
                                               u16* __restrict__ qp,
                                               u16* __restrict__ kp,
                                               u16* __restrict__ vpT) {
    const int mode = blockIdx.y;
    const float* X = (mode == 0) ? xq : (mode == 1) ? xk : xv;
    const u16*   W = WT + mode * (DK_ * F_);

    __shared__ u16 a_lds[64][40];
    __shared__ u16 w_lds[128][40];

    const int t    = threadIdx.x;
    const int lane = t & 63;
    const int wv_  = t >> 6;
    const int l15  = lane & 15, l4 = lane >> 4;
    const int row0 = blockIdx.x * 64;

    f32x4 acc[8];
#pragma unroll
    for (int j = 0; j < 8; ++j) acc[j] = f32x4{0.f, 0.f, 0.f, 0.f};

    for (int k0 = 0; k0 < F_; k0 += 32) {
        {
            int r = t >> 2, kk = (t & 3) * 8;
            const float4* src = (const float4*)(X + (size_t)(row0 + r) * F_ + k0 + kk);
            float4 f0 = src[0], f1 = src[1];
            int4 o0;
            o0.x = pack2(f0.x, f0.y); o0.y = pack2(f0.z, f0.w);
            o0.z = pack2(f1.x, f1.y); o0.w = pack2(f1.z, f1.w);
            *(int4*)&a_lds[r][kk] = o0;
        }
        {
            int c = t >> 1, kk = (t & 1) * 16;
            const int4* src = (const int4*)(W + (size_t)c * F_ + k0 + kk);
            *(int4*)&w_lds[c][kk]     = src[0];
            *(int4*)&w_lds[c][kk + 8] = src[1];
        }
        __syncthreads();

        short8 af = *(const short8*)&a_lds[wv_ * 16 + l15][l4 * 8];
        short8 bf[8];
#pragma unroll
        for (int ct = 0; ct < 8; ++ct)
            bf[ct] = *(const short8*)&w_lds[ct * 16 + l15][l4 * 8];

        if (mode < 2) {
#pragma unroll
            for (int ct = 0; ct < 8; ++ct)
                acc[ct] = __builtin_amdgcn_mfma_f32_16x16x32_bf16(af, bf[ct], acc[ct], 0, 0, 0);
        } else {
#pragma unroll
            for (int ct = 0; ct < 8; ++ct)
                acc[ct] = __builtin_amdgcn_mfma_f32_16x16x32_bf16(bf[ct], af, acc[ct], 0, 0, 0);
        }
        __syncthreads();
    }

    if (mode < 2) {
        u16* OUT = (mode == 0) ? qp : kp;
#pragma unroll
        for (int ct = 0; ct < 8; ++ct)
#pragma unroll
            for (int r = 0; r < 4; ++r) {
                int row = row0 + wv_ * 16 + l4 * 4 + r;
                int col = ct * 16 + l15;
                OUT[(size_t)row * DK_ + col] = f2bf(acc[ct][r]);
            }
    } else {
#pragma unroll
        for (int ct = 0; ct < 8; ++ct)
#pragma unroll
            for (int r = 0; r < 4; ++r) {
                int n = ct * 16 + l4 * 4 + r;
                int m = row0 + wv_ * 16 + l15;
                vpT[(size_t)n * M_ + m] = f2bf(acc[ct][r]);
            }
    }
}

// ---------------------------------------------------------------------------
// Kernel 3: flash attention v5 — work dedup.
// R9-R11 all ~50us despite schedule changes; the invariant was the d_half
// duplication (every QK MFMA + every exp computed 2x) and 32 barriered iters.
// v5: 8 waves = q_sub(2) x kv_sub(4), 64 q rows, kv-tile 128, 16 iters.
// Each wave owns its (q_sub, kv_sub) score quarter -> zero duplication; PV
// accumulates full d per wave (o4[4] -> AGPRs). Staging regs transient
// (LOADT;WRITET back-to-back after barrier — R9/R10 proved exposed load
// latency per iter is cheap). Grid 256 (b=blk&7 XCD-pin), 1 block/CU.
// ---------------------------------------------------------------------------
union attn_lds_t {
    struct {
        __align__(16) unsigned char kbuf[2][32768];  // [128 kv][256B], chunk16 ^= row&15
        __align__(16) unsigned char vbuf[2][32768];  // [128 d][256B],  chunk16 ^= row&15
    } s;
    struct { float ob[64][132]; } e;                 // epilogue combine (33.8 KB)
};

__global__ __launch_bounds__(512, 1) void attn(const u16* __restrict__ qp,
                                               const u16* __restrict__ kp,
                                               const u16* __restrict__ vpT,
                                               float* __restrict__ out) {
    __shared__ attn_lds_t u;
    __shared__ float m_l[2][4][32], l_l[2][4][2][32], gm_l[2][32], gl_l[2][32];

    const int t      = threadIdx.x;
    const int lane   = t & 63;
    const int wv_    = t >> 6;              // 0..7
    const int q_sub  = wv_ & 1;
    const int kv_sub = wv_ >> 1;            // 0..3
    const int r31    = lane & 31;
    const int hi     = lane >> 5;

    const int b  = blockIdx.x & 7;
    const int qi = blockIdx.x >> 3;          // 0..31
    const int qrow0 = b * S_ + qi * 64;
    const int kvb0  = b * S_;

    // Q as persistent B-fragments: qf[c] = Q[q][d = c*16 + hi*8 + 0..7]
    short8 qf[8];
#pragma unroll
    for (int c = 0; c < 8; ++c)
        qf[c] = *(const short8*)(qp + (size_t)(qrow0 + q_sub * 32 + r31) * DK_
                                    + c * 16 + hi * 8);

    f32x16 o4[4];
#pragma unroll
    for (int ct = 0; ct < 4; ++ct)
#pragma unroll
        for (int i = 0; i < 16; ++i) o4[ct][i] = 0.f;
    float mrun = -1.0e30f, lrun = 0.f;      // mrun cross-half uniform; lrun per-half

    // staging geometry: 512 thr x 4 int4 each for K and V (tile = 2048 int4 each)
    int kr[4], kc[4];
#pragma unroll
    for (int j = 0; j < 4; ++j) {
        int f = t + 512 * j;
        kr[j] = f >> 4; kc[j] = f & 15;     // same mapping for V
    }

#define STAGE(kvb, nb)                                                            \
    {                                                                             \
        int4 gk[4], gv[4];                                                        \
        _Pragma("unroll")                                                         \
        for (int j = 0; j < 4; ++j) {                                             \
            gk[j] = *(const int4*)(kp + (size_t)((kvb) + kr[j]) * DK_ + kc[j] * 8);\
            gv[j] = *(const int4*)(vpT + (size_t)kr[j] * M_ + (kvb) + kc[j] * 8); \
        }                                                                         \
        _Pragma("unroll")                                                         \
        for (int j = 0; j < 4; ++j) {                                             \
            *(int4*)(u.s.kbuf[nb] + kr[j] * 256 + ((kc[j] ^ (kr[j] & 15)) << 4)) = gk[j]; \
            *(int4*)(u.s.vbuf[nb] + kr[j] * 256 + ((kc[j] ^ (kr[j] & 15)) << 4)) = gv[j]; \
        }                                                                         \
    }

    STAGE(kvb0, 0);
    int cur = 0;

    for (int kt = 0; kt < 16; ++kt) {
        __syncthreads();                     // buf[cur] visible

        if (kt < 15) STAGE(kvb0 + (kt + 1) * 128, cur ^ 1);   // transient regs

        const unsigned char* kb = u.s.kbuf[cur];
        const unsigned char* vb = u.s.vbuf[cur];

        // ---- K fragments from LDS: rows kv_sub*32 + r31 of the 128-kv tile
        const int krow = kv_sub * 32 + r31;
        const int ksw  = krow & 15;
        short8 kf[8];
#pragma unroll
        for (int c = 0; c < 8; ++c)
            kf[c] = *(const short8*)(kb + krow * 256 + (((c * 2 + hi) ^ ksw) << 4));

        // ---- QK^T (own quarter), two independent 4-chains then add
        f32x16 sa, sb;
#pragma unroll
        for (int i = 0; i < 16; ++i) { sa[i] = 0.f; sb[i] = 0.f; }
#pragma unroll
        for (int c = 0; c < 4; ++c) {
            sa = __builtin_amdgcn_mfma_f32_32x32x16_bf16(kf[c],     qf[c],     sa, 0, 0, 0);
            sb = __builtin_amdgcn_mfma_f32_32x32x16_bf16(kf[c + 4], qf[c + 4], sb, 0, 0, 0);
        }
        f32x16 st;
#pragma unroll
        for (int i = 0; i < 16; ++i) st[i] = sa[i] + sb[i];

        // ---- per-lane softmax (log2 units), cross-lane only in rare defer path
        float tm = st[0];
#pragma unroll
        for (int i = 1; i < 16; ++i) tm = fmaxf(tm, st[i]);
        if (__any(tm > mrun + 8.0f)) {
            tm = fmaxf(tm, __shfl_xor(tm, 32, 64));   // make mrun half-uniform
            float mn = fmaxf(mrun, tm);
            float fs = fexp2(mrun - mn);
            mrun = mn;
            lrun *= fs;
#pragma unroll
            for (int ct = 0; ct < 4; ++ct)
#pragma unroll
                for (int i = 0; i < 16; ++i) o4[ct][i] *= fs;
        }
        float s0 = 0.f, s1 = 0.f;
#pragma unroll
        for (int i = 0; i < 16; i += 2) {
            st[i]     = fexp2(st[i] - mrun);
            st[i + 1] = fexp2(st[i + 1] - mrun);
            s0 += st[i]; s1 += st[i + 1];
        }
        lrun += s0 + s1;

        // ---- P -> bf16 B-fragments via permlane32_swap
        short8 bp[2];
#pragma unroll
        for (int ch = 0; ch < 2; ++ch) {
            unsigned int A1 = cvt_pk_bf16(st[ch * 8 + 0], st[ch * 8 + 1]);
            unsigned int A2 = cvt_pk_bf16(st[ch * 8 + 2], st[ch * 8 + 3]);
            unsigned int A3 = cvt_pk_bf16(st[ch * 8 + 4], st[ch * 8 + 5]);
            unsigned int A4 = cvt_pk_bf16(st[ch * 8 + 6], st[ch * 8 + 7]);
            pl32_swap(A1, A3);
            pl32_swap(A2, A4);
            int4 w;
            w.x = (int)A1; w.y = (int)A2; w.z = (int)A3; w.w = (int)A4;
            bp[ch] = *(short8*)&w;
        }

        // ---- PV: full d per wave, kv k-dim = this wave's 32-kv slice
#pragma unroll
        for (int ct = 0; ct < 4; ++ct) {
            const int vrow = ct * 32 + r31;
            const int vsw  = vrow & 15;
#pragma unroll
            for (int ch = 0; ch < 2; ++ch) {
                short8 vf = *(const short8*)(vb + vrow * 256
                                             + (((kv_sub * 4 + ch * 2 + hi) ^ vsw) << 4));
                o4[ct] = __builtin_amdgcn_mfma_f32_32x32x16_bf16(vf, bp[ch], o4[ct], 0, 0, 0);
            }
        }

        cur ^= 1;
    }
#undef STAGE

    // ---- epilogue: combine 4 kv_sub partials per q_sub ----
    __syncthreads();                          // all PV reads done (union reuse)
    l_l[q_sub][kv_sub][hi][r31] = lrun;
    if (lane < 32) m_l[q_sub][kv_sub][r31] = mrun;
    __syncthreads();
    if (t < 64) {
        int qs = t >> 5, qq = t & 31;
        float gm = -1.0e30f;
#pragma unroll
        for (int ks = 0; ks < 4; ++ks) gm = fmaxf(gm, m_l[qs][ks][qq]);
        float gl = 0.f;
#pragma unroll
        for (int ks = 0; ks < 4; ++ks)
            gl += (l_l[qs][ks][0][qq] + l_l[qs][ks][1][qq]) * fexp2(m_l[qs][ks][qq] - gm);
        gm_l[qs][qq] = gm;
        gl_l[qs][qq] = gl;
    }
    __syncthreads();

    const float sc = fexp2(mrun - gm_l[q_sub][r31]);
    const int qrow = q_sub * 32 + r31;
    for (int rr = 0; rr < 4; ++rr) {
        if (kv_sub == rr) {
            if (rr == 0) {
#pragma unroll
                for (int ct = 0; ct < 4; ++ct)
#pragma unroll
                    for (int i = 0; i < 16; ++i) {
                        int d = ct * 32 + (i & 3) + 8 * (i >> 2) + 4 * hi;
                        u.e.ob[qrow][d] = o4[ct][i] * sc;
                    }
            } else {
#pragma unroll
                for (int ct = 0; ct < 4; ++ct)
#pragma unroll
                    for (int i = 0; i < 16; ++i) {
                        int d = ct * 32 + (i & 3) + 8 * (i >> 2) + 4 * hi;
                        u.e.ob[qrow][d] += o4[ct][i] * sc;
                    }
            }
        }
        __syncthreads();
    }

    // ---- final store: thread t -> row t>>3 (0..63), cols (t&7)*16..+16
    {
        int row = t >> 3, d0 = (t & 7) * 16;
        float inv = 1.0f / gl_l[row >> 5][row & 31];
        float* dst = out + (size_t)(qrow0 + row) * DK_ + d0;
#pragma unroll
        for (int j = 0; j < 16; j += 4) {
            float4 v;
            v.x = u.e.ob[row][d0 + j]     * inv;
            v.y = u.e.ob[row][d0 + j + 1] * inv;
            v.z = u.e.ob[row][d0 + j + 2] * inv;
            v.w = u.e.ob[row][d0 + j + 3] * inv;
            *(float4*)(dst + j) = v;
        }
    }
}

// ---------------------------------------------------------------------------
extern "C" void kernel_launch(void* const* d_in, const int* in_sizes, int n_in,
                              void* d_out, int out_size, void* d_ws, size_t ws_size,
                              hipStream_t stream) {
    const float* q  = (const float*)d_in[0];
    const float* k  = (const float*)d_in[1];
    const float* v  = (const float*)d_in[2];
    const float* wq = (const float*)d_in[3];
    const float* wk = (const float*)d_in[4];
    const float* wv = (const float*)d_in[5];
    float* out = (float*)d_out;

    char* ws = (char*)d_ws;
    u16* WT  = (u16*)ws;                                   // 786432 B
    u16* qp  = (u16*)(ws + 786432);                        // 4 MB
    u16* kp  = (u16*)(ws + 786432 + 4194304);              // 4 MB
    u16* vpT = (u16*)(ws + 786432 + 2 * 4194304);          // 4 MB

    prep_wt<<<dim3(1536), dim3(256), 0, stream>>>(wq, wk, wv, WT);
    proj<<<dim3(256, 3), dim3(256), 0, stream>>>(q, k, v, WT, qp, kp, vpT);
    attn<<<dim3(256), dim3(512), 0, stream>>>(qp, kp, vpT, out);
}

// Round 14
// 74.519 us; speedup vs baseline: 1.1525x; 1.0253x over previous
//
#include <hip/hip_runtime.h>
#include <hip/hip_bf16.h>

#define B_ 8
#define S_ 2048
#define F_ 1024
#define DK_ 128
#define M_ (B_*S_)          // 16384

typedef unsigned short u16;
typedef short short8 __attribute__((ext_vector_type(8)));
typedef float f32x4 __attribute__((ext_vector_type(4)));
typedef float f32x16 __attribute__((ext_vector_type(16)));

__device__ __forceinline__ u16 f2bf(float f) {
    unsigned int u = __float_as_uint(f);
    u += 0x7FFFu + ((u >> 16) & 1u);    // round-to-nearest-even
    return (u16)(u >> 16);
}
__device__ __forceinline__ unsigned int pack2(float a, float b) {
    return (unsigned int)f2bf(a) | ((unsigned int)f2bf(b) << 16);
}
__device__ __forceinline__ float fexp2(float x) {
#if __has_builtin(__builtin_amdgcn_exp2f)
    return __builtin_amdgcn_exp2f(x);   // raw v_exp_f32 (2^x)
#else
    return exp2f(x);
#endif
}
__device__ __forceinline__ unsigned int cvt_pk_bf16(float lo, float hi) {
    unsigned int r;
    asm("v_cvt_pk_bf16_f32 %0, %1, %2" : "=v"(r) : "v"(lo), "v"(hi));
    return r;
}
// v_permlane32_swap_b32 a, b:  a_hi <-> b_lo.
__device__ __forceinline__ void pl32_swap(unsigned int& a, unsigned int& b) {
    asm("v_permlane32_swap_b32 %0, %1" : "+v"(a), "+v"(b));
}

// ---------------------------------------------------------------------------
// Kernel 1: W [1024][128] fp32 -> WT [3][128][1024] bf16 (transposed).
// w_q gets (1/sqrt(128)) * log2(e) folded in, so softmax uses raw exp2.
// ---------------------------------------------------------------------------
__global__ __launch_bounds__(256) void prep_wt(const float* __restrict__ wq,
                                               const float* __restrict__ wk,
                                               const float* __restrict__ wv,
                                               u16* __restrict__ WT) {
    int id = blockIdx.x * 256 + threadIdx.x;
    if (id >= 3 * DK_ * F_) return;
    int m   = id / (DK_ * F_);
    int rem = id - m * (DK_ * F_);
    int c   = rem / F_;
    int k   = rem - c * F_;
    const float* w = (m == 0) ? wq : (m == 1) ? wk : wv;
    float v = w[k * DK_ + c];
    if (m == 0) v *= 0.12751741951f;   // (1/sqrt(128)) * log2(e)
    WT[id] = f2bf(v);
}

// ---------------------------------------------------------------------------
// Kernel 2: projection GEMM (proven R2-R6 version, unchanged).
// mode 0: qp [16384][128], mode 1: kp [16384][128], mode 2: vpT [128][16384]
// ---------------------------------------------------------------------------
__global__ __launch_bounds__(256, 3) void proj(const float* __restrict__ xq,
                                               const float* __restrict__ xk,
                                               const float* __restrict__ xv,
                                               const u16* __restrict__ WT,
                                               u16* __restrict__ qp,
                                               u16* __restrict__ kp,
                                               u16* __restrict__ vpT) {
    const int mode = blockIdx.y;
    const float* X = (mode == 0) ? xq : (mode == 1) ? xk : xv;
    const u16*   W = WT + mode * (DK_ * F_);

    __shared__ u16 a_lds[64][40];
    __shared__ u16 w_lds[128][40];

    const int t    = threadIdx.x;
    const int lane = t & 63;
    const int wv_  = t >> 6;
    const int l15  = lane & 15, l4 = lane >> 4;
    const int row0 = blockIdx.x * 64;

    f32x4 acc[8];
#pragma unroll
    for (int j = 0; j < 8; ++j) acc[j] = f32x4{0.f, 0.f, 0.f, 0.f};

    for (int k0 = 0; k0 < F_; k0 += 32) {
        {
            int r = t >> 2, kk = (t & 3) * 8;
            const float4* src = (const float4*)(X + (size_t)(row0 + r) * F_ + k0 + kk);
            float4 f0 = src[0], f1 = src[1];
            int4 o0;
            o0.x = pack2(f0.x, f0.y); o0.y = pack2(f0.z, f0.w);
            o0.z = pack2(f1.x, f1.y); o0.w = pack2(f1.z, f1.w);
            *(int4*)&a_lds[r][kk] = o0;
        }
        {
            int c = t >> 1, kk = (t & 1) * 16;
            const int4* src = (const int4*)(W + (size_t)c * F_ + k0 + kk);
            *(int4*)&w_lds[c][kk]     = src[0];
            *(int4*)&w_lds[c][kk + 8] = src[1];
        }
        __syncthreads();

        short8 af = *(const short8*)&a_lds[wv_ * 16 + l15][l4 * 8];
        short8 bf[8];
#pragma unroll
        for (int ct = 0; ct < 8; ++ct)
            bf[ct] = *(const short8*)&w_lds[ct * 16 + l15][l4 * 8];

        if (mode < 2) {
#pragma unroll
            for (int ct = 0; ct < 8; ++ct)
                acc[ct] = __builtin_amdgcn_mfma_f32_16x16x32_bf16(af, bf[ct], acc[ct], 0, 0, 0);
        } else {
#pragma unroll
            for (int ct = 0; ct < 8; ++ct)
                acc[ct] = __builtin_amdgcn_mfma_f32_16x16x32_bf16(bf[ct], af, acc[ct], 0, 0, 0);
        }
        __syncthreads();
    }

    if (mode < 2) {
        u16* OUT = (mode == 0) ? qp : kp;
#pragma unroll
        for (int ct = 0; ct < 8; ++ct)
#pragma unroll
            for (int r = 0; r < 4; ++r) {
                int row = row0 + wv_ * 16 + l4 * 4 + r;
                int col = ct * 16 + l15;
                OUT[(size_t)row * DK_ + col] = f2bf(acc[ct][r]);
            }
    } else {
#pragma unroll
        for (int ct = 0; ct < 8; ++ct)
#pragma unroll
            for (int r = 0; r < 4; ++r) {
                int n = ct * 16 + l4 * 4 + r;
                int m = row0 + wv_ * 16 + l15;
                vpT[(size_t)n * M_ + m] = f2bf(acc[ct][r]);
            }
    }
}

// ---------------------------------------------------------------------------
// Kernel 3: flash attention v5.1 = R12 (passed, 76.4us) + T14 async-STAGE
// split. R12 did LOADT;WRITET back-to-back after the barrier: ds_writes
// stall ~300-500cyc on the global loads, all 8 waves in lockstep. Now:
//   barrier -> issue K loads -> kf ds_reads + QK^T (hides K loads)
//   -> write K + issue V loads -> softmax/repack (hides V loads)
//   -> write V -> vf ds_reads + PV -> next iter.
// Only 16 staging regs live at a time (K phase or V phase), keeping pressure
// ~R12 level at the 512-thr/128-VGPR cap. Data placement/swizzles/math are
// byte-identical to R12 (v13's DMA experiment failed correctness; reverted).
// ---------------------------------------------------------------------------
union attn_lds_t {
    struct {
        __align__(16) unsigned char kbuf[2][32768];  // [128 kv][256B], chunk16 ^= row&15
        __align__(16) unsigned char vbuf[2][32768];  // [128 d][256B],  chunk16 ^= row&15
    } s;
    struct { float ob[64][132]; } e;                 // epilogue combine (33.8 KB)
};

__global__ __launch_bounds__(512, 1) void attn(const u16* __restrict__ qp,
                                               const u16* __restrict__ kp,
                                               const u16* __restrict__ vpT,
                                               float* __restrict__ out) {
    __shared__ attn_lds_t u;
    __shared__ float m_l[2][4][32], l_l[2][4][2][32], gm_l[2][32], gl_l[2][32];

    const int t      = threadIdx.x;
    const int lane   = t & 63;
    const int wv_    = t >> 6;              // 0..7
    const int q_sub  = wv_ & 1;
    const int kv_sub = wv_ >> 1;            // 0..3
    const int r31    = lane & 31;
    const int hi     = lane >> 5;

    const int b  = blockIdx.x & 7;
    const int qi = blockIdx.x >> 3;          // 0..31
    const int qrow0 = b * S_ + qi * 64;
    const int kvb0  = b * S_;

    // Q as persistent B-fragments: qf[c] = Q[q][d = c*16 + hi*8 + 0..7]
    short8 qf[8];
#pragma unroll
    for (int c = 0; c < 8; ++c)
        qf[c] = *(const short8*)(qp + (size_t)(qrow0 + q_sub * 32 + r31) * DK_
                                    + c * 16 + hi * 8);

    f32x16 o4[4];
#pragma unroll
    for (int ct = 0; ct < 4; ++ct)
#pragma unroll
        for (int i = 0; i < 16; ++i) o4[ct][i] = 0.f;
    float mrun = -1.0e30f, lrun = 0.f;      // mrun cross-half uniform; lrun per-half

    // staging geometry: 512 thr x 4 int4 each for K and V (tile = 2048 int4 each)
    int kr[4], kc[4];
#pragma unroll
    for (int j = 0; j < 4; ++j) {
        int f = t + 512 * j;
        kr[j] = f >> 4; kc[j] = f & 15;     // same mapping for V
    }

#define LOADK(kvb)  { _Pragma("unroll") for (int j = 0; j < 4; ++j)               \
        gk[j] = *(const int4*)(kp + (size_t)((kvb) + kr[j]) * DK_ + kc[j] * 8); }
#define LOADV(kvb)  { _Pragma("unroll") for (int j = 0; j < 4; ++j)               \
        gv[j] = *(const int4*)(vpT + (size_t)kr[j] * M_ + (kvb) + kc[j] * 8); }
#define WRITEK(nb)  { _Pragma("unroll") for (int j = 0; j < 4; ++j)               \
        *(int4*)(u.s.kbuf[nb] + kr[j] * 256 + ((kc[j] ^ (kr[j] & 15)) << 4)) = gk[j]; }
#define WRITEV(nb)  { _Pragma("unroll") for (int j = 0; j < 4; ++j)               \
        *(int4*)(u.s.vbuf[nb] + kr[j] * 256 + ((kc[j] ^ (kr[j] & 15)) << 4)) = gv[j]; }

    {   // prologue: stage tile 0
        int4 gk[4], gv[4];
        LOADK(kvb0); WRITEK(0);
        LOADV(kvb0); WRITEV(0);
    }
    int cur = 0;

    for (int kt = 0; kt < 16; ++kt) {
        __syncthreads();                     // buf[cur] visible

        int4 gk[4], gv[4];
        const int nxt = kvb0 + (kt + 1) * 128;
        if (kt < 15) LOADK(nxt);             // K loads fly under kf reads + QK^T

        const unsigned char* kb = u.s.kbuf[cur];
        const unsigned char* vb = u.s.vbuf[cur];

        // ---- K fragments from LDS: rows kv_sub*32 + r31 of the 128-kv tile
        const int krow = kv_sub * 32 + r31;
        const int ksw  = krow & 15;
        short8 kf[8];
#pragma unroll
        for (int c = 0; c < 8; ++c)
            kf[c] = *(const short8*)(kb + krow * 256 + (((c * 2 + hi) ^ ksw) << 4));

        // ---- QK^T (own quarter), two independent 4-chains then add
        f32x16 sa, sb;
#pragma unroll
        for (int i = 0; i < 16; ++i) { sa[i] = 0.f; sb[i] = 0.f; }
#pragma unroll
        for (int c = 0; c < 4; ++c) {
            sa = __builtin_amdgcn_mfma_f32_32x32x16_bf16(kf[c],     qf[c],     sa, 0, 0, 0);
            sb = __builtin_amdgcn_mfma_f32_32x32x16_bf16(kf[c + 4], qf[c + 4], sb, 0, 0, 0);
        }
        f32x16 st;
#pragma unroll
        for (int i = 0; i < 16; ++i) st[i] = sa[i] + sb[i];

        if (kt < 15) { WRITEK(cur ^ 1); LOADV(nxt); }   // V loads fly under softmax

        // ---- per-lane softmax (log2 units), cross-lane only in rare defer path
        float tm = st[0];
#pragma unroll
        for (int i = 1; i < 16; ++i) tm = fmaxf(tm, st[i]);
        if (__any(tm > mrun + 8.0f)) {
            tm = fmaxf(tm, __shfl_xor(tm, 32, 64));   // make mrun half-uniform
            float mn = fmaxf(mrun, tm);
            float fs = fexp2(mrun - mn);
            mrun = mn;
            lrun *= fs;
#pragma unroll
            for (int ct = 0; ct < 4; ++ct)
#pragma unroll
                for (int i = 0; i < 16; ++i) o4[ct][i] *= fs;
        }
        float s0 = 0.f, s1 = 0.f;
#pragma unroll
        for (int i = 0; i < 16; i += 2) {
            st[i]     = fexp2(st[i] - mrun);
            st[i + 1] = fexp2(st[i + 1] - mrun);
            s0 += st[i]; s1 += st[i + 1];
        }
        lrun += s0 + s1;

        // ---- P -> bf16 B-fragments via permlane32_swap
        short8 bp[2];
#pragma unroll
        for (int ch = 0; ch < 2; ++ch) {
            unsigned int A1 = cvt_pk_bf16(st[ch * 8 + 0], st[ch * 8 + 1]);
            unsigned int A2 = cvt_pk_bf16(st[ch * 8 + 2], st[ch * 8 + 3]);
            unsigned int A3 = cvt_pk_bf16(st[ch * 8 + 4], st[ch * 8 + 5]);
            unsigned int A4 = cvt_pk_bf16(st[ch * 8 + 6], st[ch * 8 + 7]);
            pl32_swap(A1, A3);
            pl32_swap(A2, A4);
            int4 w;
            w.x = (int)A1; w.y = (int)A2; w.z = (int)A3; w.w = (int)A4;
            bp[ch] = *(short8*)&w;
        }

        if (kt < 15) WRITEV(cur ^ 1);        // ds_writes drain under PV

        // ---- PV: full d per wave, kv k-dim = this wave's 32-kv slice
#pragma unroll
        for (int ct = 0; ct < 4; ++ct) {
            const int vrow = ct * 32 + r31;
            const int vsw  = vrow & 15;
#pragma unroll
            for (int ch = 0; ch < 2; ++ch) {
                short8 vf = *(const short8*)(vb + vrow * 256
                                             + (((kv_sub * 4 + ch * 2 + hi) ^ vsw) << 4));
                o4[ct] = __builtin_amdgcn_mfma_f32_32x32x16_bf16(vf, bp[ch], o4[ct], 0, 0, 0);
            }
        }

        cur ^= 1;
    }
#undef LOADK
#undef LOADV
#undef WRITEK
#undef WRITEV

    // ---- epilogue: combine 4 kv_sub partials per q_sub ----
    __syncthreads();                          // all PV reads done (union reuse)
    l_l[q_sub][kv_sub][hi][r31] = lrun;
    if (lane < 32) m_l[q_sub][kv_sub][r31] = mrun;
    __syncthreads();
    if (t < 64) {
        int qs = t >> 5, qq = t & 31;
        float gm = -1.0e30f;
#pragma unroll
        for (int ks = 0; ks < 4; ++ks) gm = fmaxf(gm, m_l[qs][ks][qq]);
        float gl = 0.f;
#pragma unroll
        for (int ks = 0; ks < 4; ++ks)
            gl += (l_l[qs][ks][0][qq] + l_l[qs][ks][1][qq]) * fexp2(m_l[qs][ks][qq] - gm);
        gm_l[qs][qq] = gm;
        gl_l[qs][qq] = gl;
    }
    __syncthreads();

    const float sc = fexp2(mrun - gm_l[q_sub][r31]);
    const int qrow = q_sub * 32 + r31;
    for (int rr = 0; rr < 4; ++rr) {
        if (kv_sub == rr) {
            if (rr == 0) {
#pragma unroll
                for (int ct = 0; ct < 4; ++ct)
#pragma unroll
                    for (int i = 0; i < 16; ++i) {
                        int d = ct * 32 + (i & 3) + 8 * (i >> 2) + 4 * hi;
                        u.e.ob[qrow][d] = o4[ct][i] * sc;
                    }
            } else {
#pragma unroll
                for (int ct = 0; ct < 4; ++ct)
#pragma unroll
                    for (int i = 0; i < 16; ++i) {
                        int d = ct * 32 + (i & 3) + 8 * (i >> 2) + 4 * hi;
                        u.e.ob[qrow][d] += o4[ct][i] * sc;
                    }
            }
        }
        __syncthreads();
    }

    // ---- final store: thread t -> row t>>3 (0..63), cols (t&7)*16..+16
    {
        int row = t >> 3, d0 = (t & 7) * 16;
        float inv = 1.0f / gl_l[row >> 5][row & 31];
        float* dst = out + (size_t)(qrow0 + row) * DK_ + d0;
#pragma unroll
        for (int j = 0; j < 16; j += 4) {
            float4 v;
            v.x = u.e.ob[row][d0 + j]     * inv;
            v.y = u.e.ob[row][d0 + j + 1] * inv;
            v.z = u.e.ob[row][d0 + j + 2] * inv;
            v.w = u.e.ob[row][d0 + j + 3] * inv;
            *(float4*)(dst + j) = v;
        }
    }
}

// ---------------------------------------------------------------------------
extern "C" void kernel_launch(void* const* d_in, const int* in_sizes, int n_in,
                              void* d_out, int out_size, void* d_ws, size_t ws_size,
                              hipStream_t stream) {
    const float* q  = (const float*)d_in[0];
    const float* k  = (const float*)d_in[1];
    const float* v  = (const float*)d_in[2];
    const float* wq = (const float*)d_in[3];
    const float* wk = (const float*)d_in[4];
    const float* wv = (const float*)d_in[5];
    float* out = (float*)d_out;

    char* ws = (char*)d_ws;
    u16* WT  = (u16*)ws;                                   // 786432 B
    u16* qp  = (u16*)(ws + 786432);                        // 4 MB
    u16* kp  = (u16*)(ws + 786432 + 4194304);              // 4 MB
    u16* vpT = (u16*)(ws + 786432 + 2 * 4194304);          // 4 MB

    prep_wt<<<dim3(1536), dim3(256), 0, stream>>>(wq, wk, wv, WT);
    proj<<<dim3(256, 3), dim3(256), 0, stream>>>(q, k, v, WT, qp, kp, vpT);
    attn<<<dim3(256), dim3(512), 0, stream>>>(qp, kp, vpT, out);
}

// Round 15
// 73.741 us; speedup vs baseline: 1.1647x; 1.0106x over previous
//
#include <hip/hip_runtime.h>
#include <hip/hip_bf16.h>

#define B_ 8
#define S_ 2048
#define F_ 1024
#define DK_ 128
#define M_ (B_*S_)          // 16384

typedef unsigned short u16;
typedef short short8 __attribute__((ext_vector_type(8)));
typedef float f32x4 __attribute__((ext_vector_type(4)));
typedef float f32x16 __attribute__((ext_vector_type(16)));

__device__ __forceinline__ u16 f2bf(float f) {
    unsigned int u = __float_as_uint(f);
    u += 0x7FFFu + ((u >> 16) & 1u);    // round-to-nearest-even
    return (u16)(u >> 16);
}
__device__ __forceinline__ unsigned int pack2(float a, float b) {
    return (unsigned int)f2bf(a) | ((unsigned int)f2bf(b) << 16);
}
__device__ __forceinline__ float fexp2(float x) {
#if __has_builtin(__builtin_amdgcn_exp2f)
    return __builtin_amdgcn_exp2f(x);   // raw v_exp_f32 (2^x)
#else
    return exp2f(x);
#endif
}
__device__ __forceinline__ unsigned int cvt_pk_bf16(float lo, float hi) {
    unsigned int r;
    asm("v_cvt_pk_bf16_f32 %0, %1, %2" : "=v"(r) : "v"(lo), "v"(hi));
    return r;
}
// v_permlane32_swap_b32 a, b:  a_hi <-> b_lo.
__device__ __forceinline__ void pl32_swap(unsigned int& a, unsigned int& b) {
    asm("v_permlane32_swap_b32 %0, %1" : "+v"(a), "+v"(b));
}

// ---------------------------------------------------------------------------
// Kernel 1: W [1024][128] fp32 -> WT [3][128][1024] bf16 (transposed).
// w_q gets (1/sqrt(128)) * log2(e) folded in, so softmax uses raw exp2.
// ---------------------------------------------------------------------------
__global__ __launch_bounds__(256) void prep_wt(const float* __restrict__ wq,
                                               const float* __restrict__ wk,
                                               const float* __restrict__ wv,
                                               u16* __restrict__ WT) {
    int id = blockIdx.x * 256 + threadIdx.x;
    if (id >= 3 * DK_ * F_) return;
    int m   = id / (DK_ * F_);
    int rem = id - m * (DK_ * F_);
    int c   = rem / F_;
    int k   = rem - c * F_;
    const float* w = (m == 0) ? wq : (m == 1) ? wk : wv;
    float v = w[k * DK_ + c];
    if (m == 0) v *= 0.12751741951f;   // (1/sqrt(128)) * log2(e)
    WT[id] = f2bf(v);
}

// ---------------------------------------------------------------------------
// Kernel 2: projection GEMM (proven R2-R6 version, unchanged).
// mode 0: qp [16384][128], mode 1: kp [16384][128], mode 2: vpT [128][16384]
// ---------------------------------------------------------------------------
__global__ __launch_bounds__(256, 3) void proj(const float* __restrict__ xq,
                                               const float* __restrict__ xk,
                                               const float* __restrict__ xv,
                                               const u16* __restrict__ WT,
                                               u16* __restrict__ qp,
                                               u16* __restrict__ kp,
                                               u16* __restrict__ vpT) {
    const int mode = blockIdx.y;
    const float* X = (mode == 0) ? xq : (mode == 1) ? xk : xv;
    const u16*   W = WT + mode * (DK_ * F_);

    __shared__ u16 a_lds[64][40];
    __shared__ u16 w_lds[128][40];

    const int t    = threadIdx.x;
    const int lane = t & 63;
    const int wv_  = t >> 6;
    const int l15  = lane & 15, l4 = lane >> 4;
    const int row0 = blockIdx.x * 64;

    f32x4 acc[8];
#pragma unroll
    for (int j = 0; j < 8; ++j) acc[j] = f32x4{0.f, 0.f, 0.f, 0.f};

    for (int k0 = 0; k0 < F_; k0 += 32) {
        {
            int r = t >> 2, kk = (t & 3) * 8;
            const float4* src = (const float4*)(X + (size_t)(row0 + r) * F_ + k0 + kk);
            float4 f0 = src[0], f1 = src[1];
            int4 o0;
            o0.x = pack2(f0.x, f0.y); o0.y = pack2(f0.z, f0.w);
            o0.z = pack2(f1.x, f1.y); o0.w = pack2(f1.z, f1.w);
            *(int4*)&a_lds[r][kk] = o0;
        }
        {
            int c = t >> 1, kk = (t & 1) * 16;
            const int4* src = (const int4*)(W + (size_t)c * F_ + k0 + kk);
            *(int4*)&w_lds[c][kk]     = src[0];
            *(int4*)&w_lds[c][kk + 8] = src[1];
        }
        __syncthreads();

        short8 af = *(const short8*)&a_lds[wv_ * 16 + l15][l4 * 8];
        short8 bf[8];
#pragma unroll
        for (int ct = 0; ct < 8; ++ct)
            bf[ct] = *(const short8*)&w_lds[ct * 16 + l15][l4 * 8];

        if (mode < 2) {
#pragma unroll
            for (int ct = 0; ct < 8; ++ct)
                acc[ct] = __builtin_amdgcn_mfma_f32_16x16x32_bf16(af, bf[ct], acc[ct], 0, 0, 0);
        } else {
#pragma unroll
            for (int ct = 0; ct < 8; ++ct)
                acc[ct] = __builtin_amdgcn_mfma_f32_16x16x32_bf16(bf[ct], af, acc[ct], 0, 0, 0);
        }
        __syncthreads();
    }

    if (mode < 2) {
        u16* OUT = (mode == 0) ? qp : kp;
#pragma unroll
        for (int ct = 0; ct < 8; ++ct)
#pragma unroll
            for (int r = 0; r < 4; ++r) {
                int row = row0 + wv_ * 16 + l4 * 4 + r;
                int col = ct * 16 + l15;
                OUT[(size_t)row * DK_ + col] = f2bf(acc[ct][r]);
            }
    } else {
#pragma unroll
        for (int ct = 0; ct < 8; ++ct)
#pragma unroll
            for (int r = 0; r < 4; ++r) {
                int n = ct * 16 + l4 * 4 + r;
                int m = row0 + wv_ * 16 + l15;
                vpT[(size_t)n * M_ + m] = f2bf(acc[ct][r]);
            }
    }
}

// ---------------------------------------------------------------------------
// Kernel 3: flash attention v5.2 = R14 byte-identical EXCEPT the occupancy
// directive.  Hypothesis: R12/R14's ~200-reg wave state was silently capped
// at 128 VGPRs (R5 precedent: (512,1) -> VGPR_Count=128 + 96MB scratch) and
// spilled every iteration — explaining why attn sits ~40us when the cycle
// model says ~5-7, and why every schedule change was neutral.
// Fix: amdgpu_waves_per_eu(2) -> 256-VGPR cap (2 waves x 256 = 512-reg SIMD
// file), 8 waves/block = exactly 2/SIMD.  (m214 precedent: 512-thr attn
// with 249 VGPR, 0 spill.)
// ---------------------------------------------------------------------------
union attn_lds_t {
    struct {
        __align__(16) unsigned char kbuf[2][32768];  // [128 kv][256B], chunk16 ^= row&15
        __align__(16) unsigned char vbuf[2][32768];  // [128 d][256B],  chunk16 ^= row&15
    } s;
    struct { float ob[64][132]; } e;                 // epilogue combine (33.8 KB)
};

__global__ __launch_bounds__(512)
__attribute__((amdgpu_waves_per_eu(2)))
void attn(const u16* __restrict__ qp,
          const u16* __restrict__ kp,
          const u16* __restrict__ vpT,
          float* __restrict__ out) {
    __shared__ attn_lds_t u;
    __shared__ float m_l[2][4][32], l_l[2][4][2][32], gm_l[2][32], gl_l[2][32];

    const int t      = threadIdx.x;
    const int lane   = t & 63;
    const int wv_    = t >> 6;              // 0..7
    const int q_sub  = wv_ & 1;
    const int kv_sub = wv_ >> 1;            // 0..3
    const int r31    = lane & 31;
    const int hi     = lane >> 5;

    const int b  = blockIdx.x & 7;
    const int qi = blockIdx.x >> 3;          // 0..31
    const int qrow0 = b * S_ + qi * 64;
    const int kvb0  = b * S_;

    // Q as persistent B-fragments: qf[c] = Q[q][d = c*16 + hi*8 + 0..7]
    short8 qf[8];
#pragma unroll
    for (int c = 0; c < 8; ++c)
        qf[c] = *(const short8*)(qp + (size_t)(qrow0 + q_sub * 32 + r31) * DK_
                                    + c * 16 + hi * 8);

    f32x16 o4[4];
#pragma unroll
    for (int ct = 0; ct < 4; ++ct)
#pragma unroll
        for (int i = 0; i < 16; ++i) o4[ct][i] = 0.f;
    float mrun = -1.0e30f, lrun = 0.f;      // mrun cross-half uniform; lrun per-half

    // staging geometry: 512 thr x 4 int4 each for K and V (tile = 2048 int4 each)
    int kr[4], kc[4];
#pragma unroll
    for (int j = 0; j < 4; ++j) {
        int f = t + 512 * j;
        kr[j] = f >> 4; kc[j] = f & 15;     // same mapping for V
    }

#define LOADK(kvb)  { _Pragma("unroll") for (int j = 0; j < 4; ++j)               \
        gk[j] = *(const int4*)(kp + (size_t)((kvb) + kr[j]) * DK_ + kc[j] * 8); }
#define LOADV(kvb)  { _Pragma("unroll") for (int j = 0; j < 4; ++j)               \
        gv[j] = *(const int4*)(vpT + (size_t)kr[j] * M_ + (kvb) + kc[j] * 8); }
#define WRITEK(nb)  { _Pragma("unroll") for (int j = 0; j < 4; ++j)               \
        *(int4*)(u.s.kbuf[nb] + kr[j] * 256 + ((kc[j] ^ (kr[j] & 15)) << 4)) = gk[j]; }
#define WRITEV(nb)  { _Pragma("unroll") for (int j = 0; j < 4; ++j)               \
        *(int4*)(u.s.vbuf[nb] + kr[j] * 256 + ((kc[j] ^ (kr[j] & 15)) << 4)) = gv[j]; }

    {   // prologue: stage tile 0
        int4 gk[4], gv[4];
        LOADK(kvb0); WRITEK(0);
        LOADV(kvb0); WRITEV(0);
    }
    int cur = 0;

    for (int kt = 0; kt < 16; ++kt) {
        __syncthreads();                     // buf[cur] visible

        int4 gk[4], gv[4];
        const int nxt = kvb0 + (kt + 1) * 128;
        if (kt < 15) LOADK(nxt);             // K loads fly under kf reads + QK^T

        const unsigned char* kb = u.s.kbuf[cur];
        const unsigned char* vb = u.s.vbuf[cur];

        // ---- K fragments from LDS: rows kv_sub*32 + r31 of the 128-kv tile
        const int krow = kv_sub * 32 + r31;
        const int ksw  = krow & 15;
        short8 kf[8];
#pragma unroll
        for (int c = 0; c < 8; ++c)
            kf[c] = *(const short8*)(kb + krow * 256 + (((c * 2 + hi) ^ ksw) << 4));

        // ---- QK^T (own quarter), two independent 4-chains then add
        f32x16 sa, sb;
#pragma unroll
        for (int i = 0; i < 16; ++i) { sa[i] = 0.f; sb[i] = 0.f; }
#pragma unroll
        for (int c = 0; c < 4; ++c) {
            sa = __builtin_amdgcn_mfma_f32_32x32x16_bf16(kf[c],     qf[c],     sa, 0, 0, 0);
            sb = __builtin_amdgcn_mfma_f32_32x32x16_bf16(kf[c + 4], qf[c + 4], sb, 0, 0, 0);
        }
        f32x16 st;
#pragma unroll
        for (int i = 0; i < 16; ++i) st[i] = sa[i] + sb[i];

        if (kt < 15) { WRITEK(cur ^ 1); LOADV(nxt); }   // V loads fly under softmax

        // ---- per-lane softmax (log2 units), cross-lane only in rare defer path
        float tm = st[0];
#pragma unroll
        for (int i = 1; i < 16; ++i) tm = fmaxf(tm, st[i]);
        if (__any(tm > mrun + 8.0f)) {
            tm = fmaxf(tm, __shfl_xor(tm, 32, 64));   // make mrun half-uniform
            float mn = fmaxf(mrun, tm);
            float fs = fexp2(mrun - mn);
            mrun = mn;
            lrun *= fs;
#pragma unroll
            for (int ct = 0; ct < 4; ++ct)
#pragma unroll
                for (int i = 0; i < 16; ++i) o4[ct][i] *= fs;
        }
        float s0 = 0.f, s1 = 0.f;
#pragma unroll
        for (int i = 0; i < 16; i += 2) {
            st[i]     = fexp2(st[i] - mrun);
            st[i + 1] = fexp2(st[i + 1] - mrun);
            s0 += st[i]; s1 += st[i + 1];
        }
        lrun += s0 + s1;

        // ---- P -> bf16 B-fragments via permlane32_swap
        short8 bp[2];
#pragma unroll
        for (int ch = 0; ch < 2; ++ch) {
            unsigned int A1 = cvt_pk_bf16(st[ch * 8 + 0], st[ch * 8 + 1]);
            unsigned int A2 = cvt_pk_bf16(st[ch * 8 + 2], st[ch * 8 + 3]);
            unsigned int A3 = cvt_pk_bf16(st[ch * 8 + 4], st[ch * 8 + 5]);
            unsigned int A4 = cvt_pk_bf16(st[ch * 8 + 6], st[ch * 8 + 7]);
            pl32_swap(A1, A3);
            pl32_swap(A2, A4);
            int4 w;
            w.x = (int)A1; w.y = (int)A2; w.z = (int)A3; w.w = (int)A4;
            bp[ch] = *(short8*)&w;
        }

        if (kt < 15) WRITEV(cur ^ 1);        // ds_writes drain under PV

        // ---- PV: full d per wave, kv k-dim = this wave's 32-kv slice
#pragma unroll
        for (int ct = 0; ct < 4; ++ct) {
            const int vrow = ct * 32 + r31;
            const int vsw  = vrow & 15;
#pragma unroll
            for (int ch = 0; ch < 2; ++ch) {
                short8 vf = *(const short8*)(vb + vrow * 256
                                             + (((kv_sub * 4 + ch * 2 + hi) ^ vsw) << 4));
                o4[ct] = __builtin_amdgcn_mfma_f32_32x32x16_bf16(vf, bp[ch], o4[ct], 0, 0, 0);
            }
        }

        cur ^= 1;
    }
#undef LOADK
#undef LOADV
#undef WRITEK
#undef WRITEV

    // ---- epilogue: combine 4 kv_sub partials per q_sub ----
    __syncthreads();                          // all PV reads done (union reuse)
    l_l[q_sub][kv_sub][hi][r31] = lrun;
    if (lane < 32) m_l[q_sub][kv_sub][r31] = mrun;
    __syncthreads();
    if (t < 64) {
        int qs = t >> 5, qq = t & 31;
        float gm = -1.0e30f;
#pragma unroll
        for (int ks = 0; ks < 4; ++ks) gm = fmaxf(gm, m_l[qs][ks][qq]);
        float gl = 0.f;
#pragma unroll
        for (int ks = 0; ks < 4; ++ks)
            gl += (l_l[qs][ks][0][qq] + l_l[qs][ks][1][qq]) * fexp2(m_l[qs][ks][qq] - gm);
        gm_l[qs][qq] = gm;
        gl_l[qs][qq] = gl;
    }
    __syncthreads();

    const float sc = fexp2(mrun - gm_l[q_sub][r31]);
    const int qrow = q_sub * 32 + r31;
    for (int rr = 0; rr < 4; ++rr) {
        if (kv_sub == rr) {
            if (rr == 0) {
#pragma unroll
                for (int ct = 0; ct < 4; ++ct)
#pragma unroll
                    for (int i = 0; i < 16; ++i) {
                        int d = ct * 32 + (i & 3) + 8 * (i >> 2) + 4 * hi;
                        u.e.ob[qrow][d] = o4[ct][i] * sc;
                    }
            } else {
#pragma unroll
                for (int ct = 0; ct < 4; ++ct)
#pragma unroll
                    for (int i = 0; i < 16; ++i) {
                        int d = ct * 32 + (i & 3) + 8 * (i >> 2) + 4 * hi;
                        u.e.ob[qrow][d] += o4[ct][i] * sc;
                    }
            }
        }
        __syncthreads();
    }

    // ---- final store: thread t -> row t>>3 (0..63), cols (t&7)*16..+16
    {
        int row = t >> 3, d0 = (t & 7) * 16;
        float inv = 1.0f / gl_l[row >> 5][row & 31];
        float* dst = out + (size_t)(qrow0 + row) * DK_ + d0;
#pragma unroll
        for (int j = 0; j < 16; j += 4) {
            float4 v;
            v.x = u.e.ob[row][d0 + j]     * inv;
            v.y = u.e.ob[row][d0 + j + 1] * inv;
            v.z = u.e.ob[row][d0 + j + 2] * inv;
            v.w = u.e.ob[row][d0 + j + 3] * inv;
            *(float4*)(dst + j) = v;
        }
    }
}

// ---------------------------------------------------------------------------
extern "C" void kernel_launch(void* const* d_in, const int* in_sizes, int n_in,
                              void* d_out, int out_size, void* d_ws, size_t ws_size,
                              hipStream_t stream) {
    const float* q  = (const float*)d_in[0];
    const float* k  = (const float*)d_in[1];
    const float* v  = (const float*)d_in[2];
    const float* wq = (const float*)d_in[3];
    const float* wk = (const float*)d_in[4];
    const float* wv = (const float*)d_in[5];
    float* out = (float*)d_out;

    char* ws = (char*)d_ws;
    u16* WT  = (u16*)ws;                                   // 786432 B
    u16* qp  = (u16*)(ws + 786432);                        // 4 MB
    u16* kp  = (u16*)(ws + 786432 + 4194304);              // 4 MB
    u16* vpT = (u16*)(ws + 786432 + 2 * 4194304);          // 4 MB

    prep_wt<<<dim3(1536), dim3(256), 0, stream>>>(wq, wk, wv, WT);
    proj<<<dim3(256, 3), dim3(256), 0, stream>>>(q, k, v, WT, qp, kp, vpT);
    attn<<<dim3(256), dim3(512), 0, stream>>>(qp, kp, vpT, out);
}